// Round 5
// baseline (566.813 us; speedup 1.0000x reference)
//
#include <hip/hip_runtime.h>
#include <math.h>

#define BATCH 8192
#define TPB   32      // half-waves: 256 blocks -> 1 wave on each of 256 CUs
#define SEG   50      // 98 segments * 50 = 4900 steps (4900..4999 unobserved)

// R4 post-mortem: VGPR_Count=64 = 512/8 -- allocator targeted 8 waves/EU and
// spilled ~25 of the ~90 live values; each spill-reload carried a compiler
// s_waitcnt vmcnt(0) that drained the whole prefetch queue (compiler can't
// see asm loads in its vmcnt accounting). Fixes: amdgpu_waves_per_eu(1,1)
// unlocks 512 VGPRs (no spills -> no compiler waitcnts in the loop), and the
// 25 offset VGPRs are replaced by ONE rolling voffset bumped inside the asm.

#define REP50(M) M(0) M(1) M(2) M(3) M(4) M(5) M(6) M(7) M(8) M(9) \
  M(10) M(11) M(12) M(13) M(14) M(15) M(16) M(17) M(18) M(19) \
  M(20) M(21) M(22) M(23) M(24) M(25) M(26) M(27) M(28) M(29) \
  M(30) M(31) M(32) M(33) M(34) M(35) M(36) M(37) M(38) M(39) \
  M(40) M(41) M(42) M(43) M(44) M(45) M(46) M(47) M(48) M(49)

#define DECL_A(k) float A##k = 0.0f;
#define DECL_B(k) float B##k = 0.0f;

// one load + rolling-offset bump; rows are consumed in strictly increasing
// order kernel-wide, so a single counter serves both buffers forever.
#define LDL(k) "global_load_dword %[d" #k "], %[ob], %[sb]\n\t" \
               "v_add_u32 %[ob], 0x8000, %[ob]\n\t"

#define LD25 LDL(0) LDL(1) LDL(2) LDL(3) LDL(4) LDL(5) LDL(6) LDL(7) \
  LDL(8) LDL(9) LDL(10) LDL(11) LDL(12) LDL(13) LDL(14) LDL(15) LDL(16) \
  LDL(17) LDL(18) LDL(19) LDL(20) LDL(21) LDL(22) LDL(23) LDL(24)

#define LOAD_LO(P) asm volatile(LD25 \
  : [d0]"=v"(P##0),[d1]"=v"(P##1),[d2]"=v"(P##2),[d3]"=v"(P##3), \
    [d4]"=v"(P##4),[d5]"=v"(P##5),[d6]"=v"(P##6),[d7]"=v"(P##7), \
    [d8]"=v"(P##8),[d9]"=v"(P##9),[d10]"=v"(P##10),[d11]"=v"(P##11), \
    [d12]"=v"(P##12),[d13]"=v"(P##13),[d14]"=v"(P##14),[d15]"=v"(P##15), \
    [d16]"=v"(P##16),[d17]"=v"(P##17),[d18]"=v"(P##18),[d19]"=v"(P##19), \
    [d20]"=v"(P##20),[d21]"=v"(P##21),[d22]"=v"(P##22),[d23]"=v"(P##23), \
    [d24]"=v"(P##24),[ob]"+v"(ob) \
  : [sb]"s"(dWp))

#define LOAD_HI(P) asm volatile(LD25 \
  : [d0]"=v"(P##25),[d1]"=v"(P##26),[d2]"=v"(P##27),[d3]"=v"(P##28), \
    [d4]"=v"(P##29),[d5]"=v"(P##30),[d6]"=v"(P##31),[d7]"=v"(P##32), \
    [d8]"=v"(P##33),[d9]"=v"(P##34),[d10]"=v"(P##35),[d11]"=v"(P##36), \
    [d12]"=v"(P##37),[d13]"=v"(P##38),[d14]"=v"(P##39),[d15]"=v"(P##40), \
    [d16]"=v"(P##41),[d17]"=v"(P##42),[d18]"=v"(P##43),[d19]"=v"(P##44), \
    [d20]"=v"(P##45),[d21]"=v"(P##46),[d22]"=v"(P##47),[d23]"=v"(P##48), \
    [d24]"=v"(P##49),[ob]"+v"(ob) \
  : [sb]"s"(dWp))

// wait until only the newest 50 loads (the just-issued other buffer) remain
// outstanding => this buffer's 50 (older) have landed; ties make every use
// data-depend on the wait. Split 25+25 to keep asm operand counts modest.
#define WAIT_LO(P) asm volatile("s_waitcnt vmcnt(50)" \
  : "+v"(P##0),"+v"(P##1),"+v"(P##2),"+v"(P##3),"+v"(P##4), \
    "+v"(P##5),"+v"(P##6),"+v"(P##7),"+v"(P##8),"+v"(P##9), \
    "+v"(P##10),"+v"(P##11),"+v"(P##12),"+v"(P##13),"+v"(P##14), \
    "+v"(P##15),"+v"(P##16),"+v"(P##17),"+v"(P##18),"+v"(P##19), \
    "+v"(P##20),"+v"(P##21),"+v"(P##22),"+v"(P##23),"+v"(P##24))

#define WAIT_HI(P) asm volatile("s_waitcnt vmcnt(50)" \
  : "+v"(P##25),"+v"(P##26),"+v"(P##27),"+v"(P##28),"+v"(P##29), \
    "+v"(P##30),"+v"(P##31),"+v"(P##32),"+v"(P##33),"+v"(P##34), \
    "+v"(P##35),"+v"(P##36),"+v"(P##37),"+v"(P##38),"+v"(P##39), \
    "+v"(P##40),"+v"(P##41),"+v"(P##42),"+v"(P##43),"+v"(P##44), \
    "+v"(P##45),"+v"(P##46),"+v"(P##47),"+v"(P##48),"+v"(P##49))

#define STEP_BODY(dwv) { \
    float dw  = (dwv); \
    float pr  = dtrec * r0; \
    float ps  = pr * s; \
    float r0a = r0 * c1 + c2; \
    float sq  = sqrtf(fabsf(r0)); \
    float g   = dw * volc; \
    s  = s - ps; \
    i_ = i_ * ci + ps; \
    r0 = r0a + sq * g; }

#define STEP_A(k) STEP_BODY(A##k)
#define STEP_B(k) STEP_BODY(B##k)

__global__ __attribute__((amdgpu_flat_work_group_size(TPB, TPB),
                          amdgpu_waves_per_eu(1, 1)))
void sir_sde_kernel(const float* __restrict__ cond,
                    const float* __restrict__ dW,
                    const float* __restrict__ uu,
                    float* __restrict__ out)
{
    const int b = blockIdx.x * TPB + threadIdx.x;

    // load uu FIRST so the compiler's only vmem (cond/uu) and its waitcnts
    // all happen before any hidden asm load exists.
    const float u_in     = uu[b];
    const float inf_rate = cond[b * 4 + 0];
    const float rec      = cond[b * 4 + 1];
    const float mr       = cond[b * 4 + 2];
    const float vol      = cond[b * 4 + 3];

    const float dt    = 0.01f;
    const float r0i   = inf_rate / rec;
    const float dtrec = dt * rec;
    const float ci    = 1.0f - dtrec;       // i' = i*ci + ps
    const float c1    = 1.0f - dt * mr;     // r0' = r0*c1 + c2 + sqrt|r0|*g
    const float c2    = (dt * mr) * r0i;
    const float volc  = vol * sqrtf(dt);

    float s  = 0.99f;
    float i_ = 0.01f;
    float r0 = r0i;

    float maxv = -1.0f, maxat = 0.0f;
    float prevlx = 0.0f, sum = 0.0f, sumsq = 0.0f;
    int   reccount = 0;

    REP50(DECL_A)
    REP50(DECL_B)

    const float* dWp = dW;                    // wave-uniform SGPR base
    unsigned ob = (unsigned)b * 4u;           // rolling per-lane byte offset

    // preheader: segment 0 (rows 0..49) in flight
    LOAD_LO(A); LOAD_HI(A);

#pragma clang loop unroll(disable)
    for (int sg = 0; sg < 98; sg += 2) {
        // issue segment sg+1 (rows consumed next-but-one)
        LOAD_LO(B); LOAD_HI(B);

        // segment sg's 50 are the oldest 50 of 100 outstanding -> landed
        WAIT_LO(A); WAIT_HI(A);
        REP50(STEP_A)

        // issue segment sg+2 (last iter: rows 4900..4949, valid, unused)
        LOAD_LO(A); LOAD_HI(A);

        WAIT_LO(B); WAIT_HI(B);
        REP50(STEP_B)

        // segment sg+1 ends at t = 50*sg + 99  ==  99 (mod 100): record
        {
            float x = __builtin_isfinite(i_) ? i_ : 0.0f;   // nan_to_num
            x = fmaxf(x, 1e-5f);                            // clip
            float lx = logf(x);
            if (reccount > 0) {
                float d = lx - prevlx;
                sum   += d;
                sumsq += d * d;
            }
            prevlx = lx;
            if (x > maxv) { maxv = x; maxat = (float)reccount; } // first max
            ++reccount;
        }
    }

    // drain the final dummy batch; ties keep A regs reserved until retire
    asm volatile("s_waitcnt vmcnt(0)"
      : "+v"(A0),"+v"(A1),"+v"(A2),"+v"(A3),"+v"(A4),"+v"(A5),"+v"(A6),
        "+v"(A7),"+v"(A8),"+v"(A9),"+v"(A10),"+v"(A11),"+v"(A12),"+v"(A13),
        "+v"(A14),"+v"(A15),"+v"(A16),"+v"(A17),"+v"(A18),"+v"(A19),
        "+v"(A20),"+v"(A21),"+v"(A22),"+v"(A23),"+v"(A24) : : "memory");
    asm volatile("s_waitcnt vmcnt(0)"
      : "+v"(A25),"+v"(A26),"+v"(A27),"+v"(A28),"+v"(A29),"+v"(A30),
        "+v"(A31),"+v"(A32),"+v"(A33),"+v"(A34),"+v"(A35),"+v"(A36),
        "+v"(A37),"+v"(A38),"+v"(A39),"+v"(A40),"+v"(A41),"+v"(A42),
        "+v"(A43),"+v"(A44),"+v"(A45),"+v"(A46),"+v"(A47),"+v"(A48),
        "+v"(A49) : : "memory");

    // epilogue: std (ddof=0 over 48 diffs), max_at = (argmax + u)/49
    float mean = sum / 48.0f;
    float var  = sumsq / 48.0f - mean * mean;
    var = fmaxf(var, 0.0f);
    float volout    = sqrtf(var);
    float maxat_out = (maxat + u_in) / 49.0f;

    out[b * 3 + 0] = maxv;
    out[b * 3 + 1] = maxat_out;
    out[b * 3 + 2] = volout;
}

extern "C" void kernel_launch(void* const* d_in, const int* in_sizes, int n_in,
                              void* d_out, int out_size, void* d_ws, size_t ws_size,
                              hipStream_t stream)
{
    (void)in_sizes; (void)n_in; (void)out_size; (void)d_ws; (void)ws_size;
    const float* cond = (const float*)d_in[0];
    const float* dW   = (const float*)d_in[1];
    const float* uu   = (const float*)d_in[2];
    float* out = (float*)d_out;

    dim3 grid(BATCH / TPB), block(TPB);
    hipLaunchKernelGGL(sir_sde_kernel, grid, block, 0, stream, cond, dW, uu, out);
}